// Round 10
// baseline (16.081 us; speedup 1.0000x reference)
//
#include <hip/hip_runtime.h>
#include <math.h>

// Problem constants (B=256, N=32, D=D1=128, R=O=8)
#define NPAIR 64
#define NCENTER 2048
#define WCAP 48
#define RSLOT 32

typedef __attribute__((ext_vector_type(8))) short bfrag8;
typedef __attribute__((ext_vector_type(8))) unsigned short u16x8;
typedef __attribute__((ext_vector_type(4))) float f32x4;

__device__ __forceinline__ float gelu_f(float v) {
    return 0.5f * v * (1.0f + erff(v * 0.70710678118654752f));
}
__device__ __forceinline__ unsigned short f2bf(float f) {   // RNE fp32->bf16
    unsigned int u = __float_as_uint(f);
    return (unsigned short)((u + 0x7FFFu + ((u >> 16) & 1u)) >> 16);
}

// ONE dispatch, 1024 blocks = 64 pairs x 2 col-halves x 8 slices (R8 geometry,
// the round-space optimum). pair = blk & 63 -> XCD L2 affinity.
// Single-barrier structure: scan loads -> M loads -> ballot binning (lists in
// LDS) -> M convert+swizzled LDS write -> __syncthreads -> chunk loop with
// DIRECT global A-fragment gathers (no Xs staging, no rowid phase, no
// per-chunk barriers): each lane reads its rows' 8-float k-slices as float4
// pairs (L2-hit: rows shared by the pair's sibling blocks on the same XCD),
// converts in-reg, ds_read_b128 B-frags, 8 MFMA, gelu epilogue.
__global__ __launch_bounds__(256, 4) void fused_kernel(
    const float* __restrict__ center_h,
    const float* __restrict__ raw_neighbors,
    const float* __restrict__ Mg,
    const float* __restrict__ bias,
    const int* __restrict__ center_o,
    const int* __restrict__ s_types,
    const int* __restrict__ o_types,
    float* __restrict__ out)
{
    __shared__ __align__(16) unsigned short Mbt[64 * 128];   // 16KB [c_loc][d]
    __shared__ int list[4 * WCAP];
    __shared__ int cnts[4];

    const int t    = threadIdx.x;
    const int wave = t >> 6, lane = t & 63;
    const int pair = blockIdx.x & 63;
    const int rest = blockIdx.x >> 6;        // 0..15
    const int ch   = rest & 1;               // col-half
    const int slice = rest >> 1;             // 0..7
    const int r0 = pair >> 3, o0 = pair & 7;

    // --- scan loads first
    const int4 svv = ((const int4*)s_types)[slice * 256 + t];
    const int4 ovv = ((const int4*)o_types)[slice * 256 + t];
    const int my_b  = slice * 32 + wave * 8 + (lane & 7);
    const int my_co = center_o[my_b];

    // --- M half-matrix loads (R8-proven): thread (dblk=t>>4, lane16=t&15),
    // cols c_loc = 16*i + lane16 (i<4), d = dblk*8+r.
    const int lane16 = t & 15, dblk = t >> 4;
    float g[4][8];
    {
        const float* mp = Mg + pair * 16384 + (dblk * 8) * 128 + ch * 64;
        #pragma unroll
        for (int i = 0; i < 4; ++i)
            #pragma unroll
            for (int r = 0; r < 8; ++r)
                g[i][r] = mp[r * 128 + 16 * i + lane16];
    }

    // --- ballot compaction (deterministic; proven R4-R9 verbatim)
    int cw = 0;
    {
        const bool match = (lane < 8) && (my_co == o0);
        const unsigned long long mk = __ballot(match);
        const int pre = __builtin_amdgcn_mbcnt_hi(
            (unsigned)(mk >> 32), __builtin_amdgcn_mbcnt_lo((unsigned)mk, 0));
        if (match) {
            const int pos = cw + pre;
            if (pos < WCAP) list[wave * WCAP + pos] = my_b * 8 + r0;
        }
        cw += __popcll(mk);
    }
    {
        const int ss[4] = { svv.x, svv.y, svv.z, svv.w };
        const int oo[4] = { ovv.x, ovv.y, ovv.z, ovv.w };
        const int base_nid = slice * 1024 + t * 4;
        #pragma unroll
        for (int j = 0; j < 4; ++j) {
            const int s = ss[j] < 0 ? 0 : ss[j];
            const int o = oo[j] < 0 ? 0 : oo[j];
            const bool match = (s == r0) & (o == o0);
            const unsigned long long mk = __ballot(match);
            const int pre = __builtin_amdgcn_mbcnt_hi(
                (unsigned)(mk >> 32), __builtin_amdgcn_mbcnt_lo((unsigned)mk, 0));
            if (match) {
                const int pos = cw + pre;
                if (pos < WCAP) list[wave * WCAP + pos] = NCENTER + base_nid + j;
            }
            cw += __popcll(mk);
            if (cw > WCAP) cw = WCAP;
        }
    }
    if (lane == 0) cnts[wave] = cw;

    // --- pack + transposed swizzled write of M half into LDS (R8-proven):
    // granule dch at col c holds d = dch*8+j; g_idx = dblk ^ (c&15).
    #pragma unroll
    for (int i = 0; i < 4; ++i) {
        const int c = 16 * i + lane16;
        u16x8 w;
        #pragma unroll
        for (int r = 0; r < 8; ++r) w[r] = f2bf(g[i][r]);
        *(u16x8*)((char*)Mbt + c * 256 + ((dblk ^ lane16) << 4)) = w;
    }
    __syncthreads();   // the ONLY barrier: Mbt + lists + cnts visible

    const int c0_ = cnts[0], c1_ = cnts[1], c2_ = cnts[2];
    const int cnt = c0_ + c1_ + c2_ + cnts[3];

    const int lo16 = lane & 15, hi4 = lane >> 4;
    const int c_loc = wave * 16 + lo16;          // local col 0..63
    const int colg  = ch * 64 + c_loc;           // global col
    const float bv = bias[pair * 128 + colg];

    for (int base = 0; base < cnt; base += RSLOT) {
        // decode this lane's two A rows (positions base+lo16, base+16+lo16)
        int idA = 0, idB = 0;
        {
            int p = base + lo16;
            if (p < cnt) {
                int a = p, sw = 0;
                if (a >= c0_) { a -= c0_; sw = 1;
                    if (a >= c1_) { a -= c1_; sw = 2;
                        if (a >= c2_) { a -= c2_; sw = 3; } } }
                idA = list[sw * WCAP + a];
            }
            p = base + 16 + lo16;
            if (p < cnt) {
                int a = p, sw = 0;
                if (a >= c0_) { a -= c0_; sw = 1;
                    if (a >= c1_) { a -= c1_; sw = 2;
                        if (a >= c2_) { a -= c2_; sw = 3; } } }
                idB = list[sw * WCAP + a];
            }
        }
        const float* xA = (idA < NCENTER) ? center_h + (idA >> 3) * 128
                                          : raw_neighbors + (idA - NCENTER) * 128;
        const float* xB = (idB < NCENTER) ? center_h + (idB >> 3) * 128
                                          : raw_neighbors + (idB - NCENTER) * 128;

        // gather this lane's k-slices: for MFMA k, floats k*32 + hi4*8 .. +7
        float4 fa[4][2], fb[4][2];
        #pragma unroll
        for (int k = 0; k < 4; ++k) {
            const int off = k * 32 + hi4 * 8;
            fa[k][0] = *(const float4*)(xA + off);
            fa[k][1] = *(const float4*)(xA + off + 4);
            fb[k][0] = *(const float4*)(xB + off);
            fb[k][1] = *(const float4*)(xB + off + 4);
        }

        f32x4 accA = {bv, bv, bv, bv};
        f32x4 accC = accA;
        #pragma unroll
        for (int k = 0; k < 4; ++k) {
            bfrag8 aA, aB;
            #pragma unroll
            for (int e = 0; e < 4; ++e) {
                aA[e]     = (short)f2bf(((const float*)&fa[k][0])[e]);
                aA[e + 4] = (short)f2bf(((const float*)&fa[k][1])[e]);
                aB[e]     = (short)f2bf(((const float*)&fb[k][0])[e]);
                aB[e + 4] = (short)f2bf(((const float*)&fb[k][1])[e]);
            }
            const int dch = 4 * k + hi4;
            const bfrag8 b0 = *(const bfrag8*)((const char*)Mbt + c_loc * 256 + ((dch ^ lo16) << 4));
            accA = __builtin_amdgcn_mfma_f32_16x16x32_bf16(aA, b0, accA, 0, 0, 0);
            accC = __builtin_amdgcn_mfma_f32_16x16x32_bf16(aB, b0, accC, 0, 0, 0);
        }

        // epilogue: D col = lane&15 (-> colg), row-in-tile = hi4*4 + j.
        // decode output row ids per j (per-lane LDS reads, uniform-ish).
        #pragma unroll
        for (int j = 0; j < 4; ++j) {
            int p = base + hi4 * 4 + j;
            if (p < cnt) {
                int a = p, sw = 0;
                if (a >= c0_) { a -= c0_; sw = 1;
                    if (a >= c1_) { a -= c1_; sw = 2;
                        if (a >= c2_) { a -= c2_; sw = 3; } } }
                out[list[sw * WCAP + a] * 128 + colg] = gelu_f(accA[j]);
            }
            p = base + 16 + hi4 * 4 + j;
            if (p < cnt) {
                int a = p, sw = 0;
                if (a >= c0_) { a -= c0_; sw = 1;
                    if (a >= c1_) { a -= c1_; sw = 2;
                        if (a >= c2_) { a -= c2_; sw = 3; } } }
                out[list[sw * WCAP + a] * 128 + colg] = gelu_f(accC[j]);
            }
        }
    }
}

extern "C" void kernel_launch(void* const* d_in, const int* in_sizes, int n_in,
                              void* d_out, int out_size, void* d_ws, size_t ws_size,
                              hipStream_t stream) {
    const float* center_h      = (const float*)d_in[0];
    const float* raw_neighbors = (const float*)d_in[1];
    const float* M             = (const float*)d_in[2];
    const float* bias          = (const float*)d_in[3];
    const int*   center_o      = (const int*)d_in[4];
    const int*   s_types       = (const int*)d_in[5];
    const int*   o_types       = (const int*)d_in[6];
    float* out = (float*)d_out;

    fused_kernel<<<dim3(NPAIR * 16), dim3(256), 0, stream>>>(
        center_h, raw_neighbors, M, bias, center_o, s_types, o_types, out);
}

// Round 11
// 12.080 us; speedup vs baseline: 1.3312x; 1.3312x over previous
//
#include <hip/hip_runtime.h>
#include <math.h>

// Problem constants (B=256, N=32, D=D1=128, R=O=8)
#define NPAIR 64
#define NCENTER 2048
#define WCAP 48
#define RSLOT 32

typedef __attribute__((ext_vector_type(8))) short bfrag8;
typedef __attribute__((ext_vector_type(8))) unsigned short u16x8;
typedef __attribute__((ext_vector_type(4))) float f32x4;

__device__ __forceinline__ float gelu_f(float v) {
    return 0.5f * v * (1.0f + erff(v * 0.70710678118654752f));
}
__device__ __forceinline__ unsigned short f2bf(float f) {   // RNE fp32->bf16
    unsigned int u = __float_as_uint(f);
    return (unsigned short)((u + 0x7FFFu + ((u >> 16) & 1u)) >> 16);
}

// ONE dispatch, 1024 blocks = 64 pairs x 2 col-halves x 8 slices.
// pair = blk & 63 (XCD L2 affinity: blk%8 == pair%8). Per block:
//  - convert its pair's HALF-matrix (64 cols x 128 d) fp32->bf16 transposed
//    into LDS [c][d], 4-bit XOR swizzle g = dch ^ (c&15): conflict-free b128
//    reads AND writes.
//  - ballot-bin its slice's rows (b in [32s,+32), nid in [1024s,+1024)) —
//    deterministic (fixed lane->id map, mbcnt prefix), proven R4-R8.
//  - per 32-row chunk: stage x rows bf16 into LDS (g = chg ^ (slot&15)),
//    then mfma_f32_16x16x32_bf16: each wave 1 col-tile x 2 row-tiles x 4 k.
// 4 blocks/CU (25KB LDS, launch_bounds 256,4): best measured geometry
// (R9 quarter-split with 8/CU and R10 direct-gather both regressed).
__global__ __launch_bounds__(256, 4) void fused_kernel(
    const float* __restrict__ center_h,
    const float* __restrict__ raw_neighbors,
    const float* __restrict__ Mg,
    const float* __restrict__ bias,
    const int* __restrict__ center_o,
    const int* __restrict__ s_types,
    const int* __restrict__ o_types,
    float* __restrict__ out)
{
    __shared__ __align__(16) unsigned short Mbt[64 * 128];   // 16KB [c_loc][d]
    __shared__ __align__(16) unsigned short Xs[RSLOT * 128]; // 8KB  [slot][d]
    __shared__ int list[4 * WCAP];
    __shared__ int cnts[4];
    __shared__ int rowid[RSLOT];

    const int t    = threadIdx.x;
    const int wave = t >> 6, lane = t & 63;
    const int pair = blockIdx.x & 63;
    const int rest = blockIdx.x >> 6;        // 0..15
    const int ch   = rest & 1;               // col-half
    const int slice = rest >> 1;             // 0..7
    const int r0 = pair >> 3, o0 = pair & 7;

    // --- scan loads first (FIFO vmcnt: ballot waits only on these)
    const int4 svv = ((const int4*)s_types)[slice * 256 + t];
    const int4 ovv = ((const int4*)o_types)[slice * 256 + t];
    const int my_b  = slice * 32 + wave * 8 + (lane & 7);
    const int my_co = center_o[my_b];

    // --- M half-matrix loads: thread (dblk=t>>4, lane16=t&15) reads cols
    // c_loc = 16*i + lane16 (i<4), d = dblk*8+r (r<8). Strided dwords:
    // each instr = 4x 64B segments; granule writes are lane-distinct.
    const int lane16 = t & 15, dblk = t >> 4;
    float g[4][8];
    {
        const float* mp = Mg + pair * 16384 + (dblk * 8) * 128 + ch * 64;
        #pragma unroll
        for (int i = 0; i < 4; ++i)
            #pragma unroll
            for (int r = 0; r < 8; ++r)
                g[i][r] = mp[r * 128 + 16 * i + lane16];
    }

    // --- ballot compaction (deterministic; proven R4-R8 verbatim)
    int cw = 0;
    {
        const bool match = (lane < 8) && (my_co == o0);
        const unsigned long long mk = __ballot(match);
        const int pre = __builtin_amdgcn_mbcnt_hi(
            (unsigned)(mk >> 32), __builtin_amdgcn_mbcnt_lo((unsigned)mk, 0));
        if (match) {
            const int pos = cw + pre;
            if (pos < WCAP) list[wave * WCAP + pos] = my_b * 8 + r0;
        }
        cw += __popcll(mk);
    }
    {
        const int ss[4] = { svv.x, svv.y, svv.z, svv.w };
        const int oo[4] = { ovv.x, ovv.y, ovv.z, ovv.w };
        const int base_nid = slice * 1024 + t * 4;
        #pragma unroll
        for (int j = 0; j < 4; ++j) {
            const int s = ss[j] < 0 ? 0 : ss[j];
            const int o = oo[j] < 0 ? 0 : oo[j];
            const bool match = (s == r0) & (o == o0);
            const unsigned long long mk = __ballot(match);
            const int pre = __builtin_amdgcn_mbcnt_hi(
                (unsigned)(mk >> 32), __builtin_amdgcn_mbcnt_lo((unsigned)mk, 0));
            if (match) {
                const int pos = cw + pre;
                if (pos < WCAP) list[wave * WCAP + pos] = NCENTER + base_nid + j;
            }
            cw += __popcll(mk);
            if (cw > WCAP) cw = WCAP;
        }
    }
    if (lane == 0) cnts[wave] = cw;

    // --- pack + transposed swizzled write of M half into LDS
    // granule dch at col c holds d = dch*8+j; write g_idx = dblk ^ (c&15);
    // per instr c&15 = lane16 -> all 16 granule slots distinct: conflict-free.
    #pragma unroll
    for (int i = 0; i < 4; ++i) {
        const int c = 16 * i + lane16;
        u16x8 w;
        #pragma unroll
        for (int r = 0; r < 8; ++r) w[r] = f2bf(g[i][r]);
        *(u16x8*)((char*)Mbt + c * 256 + ((dblk ^ lane16) << 4)) = w;
    }
    __syncthreads();   // Mbt + lists + cnts visible

    const int c0_ = cnts[0], c1_ = cnts[1], c2_ = cnts[2];
    const int cnt = c0_ + c1_ + c2_ + cnts[3];

    const int lo16 = lane & 15, hi4 = lane >> 4;
    const int c_loc = wave * 16 + lo16;          // local col 0..63
    const int colg  = ch * 64 + c_loc;           // global col
    const float bv = bias[pair * 128 + colg];

    for (int base = 0; base < cnt; base += RSLOT) {
        const int csz = (cnt - base < RSLOT) ? (cnt - base) : RSLOT;

        if (t < RSLOT) {
            int id = -1;
            int a = base + t;
            if (a < cnt) {
                int sw = 0;
                if (a >= c0_) { a -= c0_; sw = 1;
                    if (a >= c1_) { a -= c1_; sw = 2;
                        if (a >= c2_) { a -= c2_; sw = 3; } } }
                id = list[sw * WCAP + a];
            }
            rowid[t] = id;
        }
        __syncthreads();   // rowid visible

        // stage x rows (bf16, swizzled g = chg ^ (slot&15)); pad rows zero.
        // per instr: 16-lane cluster has slot fixed, chg 0..15 -> distinct.
        #pragma unroll
        for (int i = 0; i < 2; ++i) {
            const int flat = i * 256 + t;          // 32 slots x 16 granules
            const int slot = flat >> 4, chg = flat & 15;
            const int id = rowid[slot];
            u16x8 w = {0, 0, 0, 0, 0, 0, 0, 0};
            if (id >= 0) {
                const float* xp = (id < NCENTER) ? center_h + (id >> 3) * 128
                                                 : raw_neighbors + (id - NCENTER) * 128;
                const float4 x0 = *(const float4*)(xp + chg * 8);
                const float4 x1 = *(const float4*)(xp + chg * 8 + 4);
                w[0] = f2bf(x0.x); w[1] = f2bf(x0.y); w[2] = f2bf(x0.z); w[3] = f2bf(x0.w);
                w[4] = f2bf(x1.x); w[5] = f2bf(x1.y); w[6] = f2bf(x1.z); w[7] = f2bf(x1.w);
            }
            *(u16x8*)((char*)Xs + slot * 256 + ((chg ^ (slot & 15)) << 4)) = w;
        }
        __syncthreads();   // Xs visible

        // MFMA: A-frag lane(row=lo16/hi4): k = hi4*8+j -> granule dch = 4k+hi4.
        // rowA & 15 == rowB & 15 == lo16 -> shared swizzle key.
        f32x4 accA = {bv, bv, bv, bv};
        f32x4 accC = accA;
        #pragma unroll
        for (int k = 0; k < 4; ++k) {
            const int dch = 4 * k + hi4;
            const int gsl = (dch ^ lo16) << 4;
            const bfrag8 aA = *(const bfrag8*)((const char*)Xs  + lo16 * 256 + gsl);
            const bfrag8 aB = *(const bfrag8*)((const char*)Xs  + (16 + lo16) * 256 + gsl);
            const bfrag8 b0 = *(const bfrag8*)((const char*)Mbt + c_loc * 256 + gsl);
            accA = __builtin_amdgcn_mfma_f32_16x16x32_bf16(aA, b0, accA, 0, 0, 0);
            accC = __builtin_amdgcn_mfma_f32_16x16x32_bf16(aB, b0, accC, 0, 0, 0);
        }

        // epilogue: D col = lane&15 (-> colg), row-in-tile = hi4*4 + j
        #pragma unroll
        for (int j = 0; j < 4; ++j) {
            const int sA = hi4 * 4 + j;
            if (sA < csz) out[rowid[sA] * 128 + colg] = gelu_f(accA[j]);
            const int sB = 16 + hi4 * 4 + j;
            if (sB < csz) out[rowid[sB] * 128 + colg] = gelu_f(accC[j]);
        }
        __syncthreads();   // protect Xs/rowid before next chunk
    }
}

extern "C" void kernel_launch(void* const* d_in, const int* in_sizes, int n_in,
                              void* d_out, int out_size, void* d_ws, size_t ws_size,
                              hipStream_t stream) {
    const float* center_h      = (const float*)d_in[0];
    const float* raw_neighbors = (const float*)d_in[1];
    const float* M             = (const float*)d_in[2];
    const float* bias          = (const float*)d_in[3];
    const int*   center_o      = (const int*)d_in[4];
    const int*   s_types       = (const int*)d_in[5];
    const int*   o_types       = (const int*)d_in[6];
    float* out = (float*)d_out;

    fused_kernel<<<dim3(NPAIR * 16), dim3(256), 0, stream>>>(
        center_h, raw_neighbors, M, bias, center_o, s_types, o_types, out);
}